// Round 5
// baseline (177.465 us; speedup 1.0000x reference)
//
#include <hip/hip_runtime.h>
#include <hip/hip_bf16.h>
#include <math.h>

#define BATCH   4096
#define DIM     1024
#define NGROUPS 1024
#define INV_T   10.0f
#define RANK_W  0.1f
#define SCORE_W 0.01f

#define BI 256       // q rows per block
#define BJ 256       // a rows per block
#define KC 32        // k per stage
#define NFRAG_Q (BI/16)          // 16
#define NFRAG   (BI/16 + BJ/16)  // 32 fragments per stage
#define FRAG_ELEMS 512           // 16 rows x 32 k bf16

typedef float  floatx4 __attribute__((ext_vector_type(4)));
typedef __bf16 bf16x8  __attribute__((ext_vector_type(8)));
typedef __bf16 bf16x4  __attribute__((ext_vector_type(4)));

// async 16B/lane global->LDS: LDS dest is wave-uniform base + lane*16
#define ASYNC_COPY16(gptr, lptr)                                              \
    __builtin_amdgcn_global_load_lds(                                         \
        (const __attribute__((address_space(1))) void*)(gptr),                \
        (__attribute__((address_space(3))) void*)(lptr), 16, 0, 0)

// ---------------------------------------------------------------------------
// Kernel 1: prep. Blocks [0,1024): per-group weights. Blocks [1024,2048):
// fp32 -> bf16 conversion of Q and A into ws.
// ---------------------------------------------------------------------------
__global__ __launch_bounds__(256) void prep_kernel(
    const float* __restrict__ Q, const float* __restrict__ A,
    __bf16* __restrict__ Qb, __bf16* __restrict__ Ab,
    const int* __restrict__ qid, const float* __restrict__ ranks,
    const float* __restrict__ scores, float* __restrict__ w)
{
    const int tid = threadIdx.x;

    if (blockIdx.x >= NGROUPS) {
        const int cid = blockIdx.x - NGROUPS;          // 0..1023
        const int n4  = BATCH * DIM / 4;               // 1M float4 per matrix
        for (int i = cid * 256 + tid; i < n4; i += 1024 * 256) {
            float4 v = ((const float4*)Q)[i];
            bf16x4 b;
            b[0] = (__bf16)v.x; b[1] = (__bf16)v.y;
            b[2] = (__bf16)v.z; b[3] = (__bf16)v.w;
            ((bf16x4*)Qb)[i] = b;
            v = ((const float4*)A)[i];
            b[0] = (__bf16)v.x; b[1] = (__bf16)v.y;
            b[2] = (__bf16)v.z; b[3] = (__bf16)v.w;
            ((bf16x4*)Ab)[i] = b;
        }
        return;
    }

    // ---- group-weight part: one block (256 threads) per group ----
    const int g = blockIdx.x, lane = tid & 63, wv = tid >> 6;
    __shared__ float rmax[4], rmin[4], rsum[4];

    float gmax = -INFINITY, gmin = INFINITY;
    for (int j = tid; j < BATCH; j += 256) {
        if (qid[j] == g) {
            float s = scores[j];
            gmax = fmaxf(gmax, s);
            gmin = fminf(gmin, s);
        }
    }
    #pragma unroll
    for (int d = 1; d < 64; d <<= 1) {
        gmax = fmaxf(gmax, __shfl_xor(gmax, d, 64));
        gmin = fminf(gmin, __shfl_xor(gmin, d, 64));
    }
    if (lane == 0) { rmax[wv] = gmax; rmin[wv] = gmin; }
    __syncthreads();
    gmax = fmaxf(fmaxf(rmax[0], rmax[1]), fmaxf(rmax[2], rmax[3]));
    gmin = fminf(fminf(rmin[0], rmin[1]), fminf(rmin[2], rmin[3]));
    const float denom     = gmax - gmin;
    const float inv_denom = (denom > 0.f) ? 1.f / denom : 0.f;

    float lsum = 0.f;
    for (int j = tid; j < BATCH; j += 256) {
        if (qid[j] == g) {
            float norm = (scores[j] - gmin) * inv_denom;
            float u = __expf(-RANK_W * ranks[j] + SCORE_W * norm);
            w[j] = u;             // unnormalized; this thread owns j
            lsum += u;
        }
    }
    #pragma unroll
    for (int d = 1; d < 64; d <<= 1) lsum += __shfl_xor(lsum, d, 64);
    if (lane == 0) rsum[wv] = lsum;
    __syncthreads();
    const float wsum = rsum[0] + rsum[1] + rsum[2] + rsum[3];
    const float inv  = (wsum > 0.f) ? 1.f / wsum : 0.f;
    for (int j = tid; j < BATCH; j += 256) {
        if (qid[j] == g) w[j] *= inv;
    }
}

// ---------------------------------------------------------------------------
// Kernel 2: fused sim = (Qb Ab^T)/T with online per-row (max, sumexp,
// weighted-sum, argmax) partials per 64-col slice.
// 256x256 block tile, 16 waves of 64x64, fragment-major LDS (0 conflicts),
// double-buffered global_load_lds prefetch, 1 barrier/iter, XCD-swizzled
// 1D grid (256 blocks, assumes block->XCD = blockIdx % 8).
// ---------------------------------------------------------------------------
__global__ __launch_bounds__(1024, 4) void fused_simloss_kernel(
    const __bf16* __restrict__ Qb, const __bf16* __restrict__ Ab,
    const int* __restrict__ qid, const float* __restrict__ w,
    float* __restrict__ Pm, float* __restrict__ Pl, float* __restrict__ Ps,
    float* __restrict__ Pbv, int* __restrict__ Pbi)
{
    // fragment-major: fragment f (16 rows x 32 k) at [f*512, f*512+512);
    // lane's 16B granule at f*512 + lane*8 holds row (lane&15),
    // k = (lane>>4)*8..+7 == exact MFMA operand layout. Frags 0..15 = Q,
    // frags 16..31 = A. Two buffers for prefetch distance 1.
    __shared__ __bf16 sbuf[2][NFRAG * FRAG_ELEMS];   // 2 x 32 KB

    // XCD swizzle: 32 blocks of XCD x form a 4(ib) x 8(jb) region -> panel
    // footprint 6 MB vs 16 MB unswizzled.
    const int bid = blockIdx.x;                 // 0..255
    const int xcd = bid & 7, s = bid >> 3;      // s: 0..31
    const int ib = (xcd >> 1) * 4 + (s & 3);    // 0..15
    const int jb = (xcd & 1) * 8 + (s >> 2);    // 0..15
    const int i0 = ib * BI, j0 = jb * BJ;

    const int tid = threadIdx.x, wid = tid >> 6, lane = tid & 63;
    const int wm = wid >> 2, wn = wid & 3;      // 4x4 wave grid, 64x64 tiles
    const int quad = lane >> 4, l16 = lane & 15;

    floatx4 acc[4][4];
    #pragma unroll
    for (int m = 0; m < 4; ++m)
        #pragma unroll
        for (int n = 0; n < 4; ++n)
            #pragma unroll
            for (int c = 0; c < 4; ++c) acc[m][n][c] = 0.f;

    // staging: wave `wid` owns fragments f = wid*2, wid*2+1
    const int lr = lane & 15;
    const int lk = (lane >> 4) * 8;
    const __bf16* src[2];
    #pragma unroll
    for (int c = 0; c < 2; ++c) {
        const int f = wid * 2 + c;
        src[c] = (f < NFRAG_Q)
               ? Qb + (size_t)(i0 + f * 16 + lr) * DIM + lk
               : Ab + (size_t)(j0 + (f - NFRAG_Q) * 16 + lr) * DIM + lk;
    }

    #define STAGE(buf, k0)                                                    \
        do {                                                                  \
            _Pragma("unroll")                                                 \
            for (int c = 0; c < 2; ++c)                                       \
                ASYNC_COPY16(src[c] + (k0),                                   \
                             &sbuf[buf][(wid * 2 + c) * FRAG_ELEMS]);         \
        } while (0)

    STAGE(0, 0);   // prefetch stage 0

    for (int t = 0; t < DIM / KC; ++t) {
        __syncthreads();   // drains buf[t&1] copies (issued 1 iter ago) and
                           // orders prev reads of buf[(t+1)&1] before rewrite
        if (t + 1 < DIM / KC) STAGE((t + 1) & 1, (t + 1) * KC);

        const __bf16* cur = sbuf[t & 1];
        bf16x8 qf[4], af[4];
        #pragma unroll
        for (int mf = 0; mf < 4; ++mf)
            qf[mf] = *(const bf16x8*)&cur[(wm * 4 + mf) * FRAG_ELEMS + lane * 8];
        #pragma unroll
        for (int nf = 0; nf < 4; ++nf)
            af[nf] = *(const bf16x8*)&cur[(NFRAG_Q + wn * 4 + nf) * FRAG_ELEMS + lane * 8];
        #pragma unroll
        for (int nf = 0; nf < 4; ++nf)
            #pragma unroll
            for (int mf = 0; mf < 4; ++mf)
                acc[mf][nf] = __builtin_amdgcn_mfma_f32_16x16x32_bf16(
                    qf[mf], af[nf], acc[mf][nf], 0, 0, 0);
    }
    #undef STAGE

    // ---- epilogue: online (m, l, s, argmax) per row within 64-col slice
    int cq[4]; float cw[4];
    #pragma unroll
    for (int n = 0; n < 4; ++n) {
        int col = j0 + wn * 64 + n * 16 + l16;
        cq[n] = qid[col];
        cw[n] = w[col];
    }
    const int slice = jb * 4 + wn;             // 0..63

    #pragma unroll
    for (int m = 0; m < 4; ++m) {
        #pragma unroll
        for (int reg = 0; reg < 4; ++reg) {
            const int row = i0 + wm * 64 + m * 16 + quad * 4 + reg;
            const int rq  = qid[row];

            float v[4];
            #pragma unroll
            for (int n = 0; n < 4; ++n) v[n] = acc[m][n][reg] * INV_T;

            float lm = fmaxf(fmaxf(v[0], v[1]), fmaxf(v[2], v[3]));
            float ll = __expf(v[0] - lm) + __expf(v[1] - lm) +
                       __expf(v[2] - lm) + __expf(v[3] - lm);
            float ls = 0.f;
            #pragma unroll
            for (int n = 0; n < 4; ++n) ls += (cq[n] == rq) ? cw[n] * v[n] : 0.f;

            float bv = v[0];
            int   bi = j0 + wn * 64 + l16;
            #pragma unroll
            for (int n = 1; n < 4; ++n) {
                int c = j0 + wn * 64 + n * 16 + l16;
                if (v[n] > bv) { bv = v[n]; bi = c; }
            }

            #pragma unroll
            for (int d = 1; d < 16; d <<= 1) {
                float om  = __shfl_xor(lm, d, 64);
                float ol  = __shfl_xor(ll, d, 64);
                float os  = __shfl_xor(ls, d, 64);
                float obv = __shfl_xor(bv, d, 64);
                int   obi = __shfl_xor(bi, d, 64);
                float nm = fmaxf(lm, om);
                ll = ll * __expf(lm - nm) + ol * __expf(om - nm);
                lm = nm;
                ls += os;
                if (obv > bv || (obv == bv && obi < bi)) { bv = obv; bi = obi; }
            }
            if (l16 == 0) {
                int idx = row * 64 + slice;
                Pm[idx] = lm; Pl[idx] = ll; Ps[idx] = ls;
                Pbv[idx] = bv; Pbi[idx] = bi;
            }
        }
    }
}

// ---------------------------------------------------------------------------
// Kernel 3: merge 64 slice-partials per row -> loss/acc contributions,
// finished with per-block atomics into out[0..1] (out pre-zeroed).
// ---------------------------------------------------------------------------
__global__ __launch_bounds__(256) void row_reduce_kernel(
    const float* __restrict__ Pm, const float* __restrict__ Pl,
    const float* __restrict__ Ps, const float* __restrict__ Pbv,
    const int* __restrict__ Pbi, const int* __restrict__ qid,
    float* __restrict__ out)
{
    const int wv   = threadIdx.x >> 6;
    const int r    = blockIdx.x * 4 + wv;
    const int lane = threadIdx.x & 63;
    const int idx  = r * 64 + lane;

    float m = Pm[idx], l = Pl[idx], s = Ps[idx], bv = Pbv[idx];
    int   bi = Pbi[idx];

    #pragma unroll
    for (int d = 1; d < 64; d <<= 1) {
        float om  = __shfl_xor(m, d, 64);
        float ol  = __shfl_xor(l, d, 64);
        float os  = __shfl_xor(s, d, 64);
        float obv = __shfl_xor(bv, d, 64);
        int   obi = __shfl_xor(bi, d, 64);
        float nm = fmaxf(m, om);
        l = l * __expf(m - nm) + ol * __expf(om - nm);
        m = nm;
        s += os;
        if (obv > bv || (obv == bv && obi < bi)) { bv = obv; bi = obi; }
    }

    __shared__ float sm[4], si[4];
    if (lane == 0) {
        sm[wv] = (m + logf(l)) - s;
        si[wv] = (qid[bi] == qid[r]) ? 1.f : 0.f;
    }
    __syncthreads();
    if (threadIdx.x == 0) {
        float t1 = (sm[0] + sm[1]) + (sm[2] + sm[3]);
        float t2 = (si[0] + si[1]) + (si[2] + si[3]);
        atomicAdd(&out[0], t1 * (1.f / (float)BATCH));
        atomicAdd(&out[1], t2 * (1.f / (float)BATCH));
    }
}

// ---------------------------------------------------------------------------
extern "C" void kernel_launch(void* const* d_in, const int* in_sizes, int n_in,
                              void* d_out, int out_size, void* d_ws, size_t ws_size,
                              hipStream_t stream)
{
    const float* Q      = (const float*)d_in[0];
    const float* A      = (const float*)d_in[1];
    const int*   qid    = (const int*)d_in[2];
    const float* ranks  = (const float*)d_in[3];
    const float* scores = (const float*)d_in[4];
    float* out = (float*)d_out;

    // ws layout: Qb[4M bf16]=8MB | Ab[4M bf16]=8MB | w[4096] |
    //            Pm,Pl,Ps,Pbv[262144] | Pbi[262144]
    __bf16* Qb = (__bf16*)d_ws;
    __bf16* Ab = Qb + (size_t)BATCH * DIM;
    float* w       = (float*)(Ab + (size_t)BATCH * DIM);
    float* Pm      = w + BATCH;
    float* Pl      = Pm + BATCH * 64;
    float* Ps      = Pl + BATCH * 64;
    float* Pbv     = Ps + BATCH * 64;
    int*   Pbi     = (int*)(Pbv + BATCH * 64);

    hipMemsetAsync(out, 0, 2 * sizeof(float), stream);

    prep_kernel<<<2048, 256, 0, stream>>>(Q, A, Qb, Ab, qid, ranks, scores, w);

    fused_simloss_kernel<<<256, 1024, 0, stream>>>(Qb, Ab, qid, w, Pm, Pl, Ps, Pbv, Pbi);

    row_reduce_kernel<<<BATCH / 4, 256, 0, stream>>>(Pm, Pl, Ps, Pbv, Pbi, qid, out);
}

// Round 6
// 162.747 us; speedup vs baseline: 1.0904x; 1.0904x over previous
//
#include <hip/hip_runtime.h>
#include <hip/hip_bf16.h>
#include <math.h>

#define BATCH   4096
#define DIM     1024
#define NGROUPS 1024
#define INV_T   10.0f
#define RANK_W  0.1f
#define SCORE_W 0.01f

#define BI 256       // q rows per block
#define BJ 256       // a rows per block
#define KC 32        // k per stage
#define NSTAGE (DIM/KC)          // 32
#define NFRAG_Q (BI/16)          // 16
#define NFRAG   (BI/16 + BJ/16)  // 32 fragments per stage
#define FRAG_ELEMS 512           // 16 rows x 32 k bf16

typedef float  floatx4 __attribute__((ext_vector_type(4)));
typedef __bf16 bf16x8  __attribute__((ext_vector_type(8)));
typedef __bf16 bf16x4  __attribute__((ext_vector_type(4)));

// async 16B/lane global->LDS: LDS dest is wave-uniform base + lane*16
#define ASYNC_COPY16(gptr, lptr)                                              \
    __builtin_amdgcn_global_load_lds(                                         \
        (const __attribute__((address_space(1))) void*)(gptr),                \
        (__attribute__((address_space(3))) void*)(lptr), 16, 0, 0)

// Packed layout: matrix -> 16 panels (256 rows). Panel p, stage t, frag fi:
// 512 bf16 at ((p*32 + t)*16 + fi)*512. Granule g (=lane) holds row
// (g&15), k = t*32 + (g>>4)*8 .. +7  == exact MFMA A/B operand order.

// ---------------------------------------------------------------------------
// Kernel 1: prep. Blocks [0,1024): per-group weights.
// Blocks [1024, 1024+4096): pack fp32 Q/A -> fragment-major bf16 Qp/Ap.
// ---------------------------------------------------------------------------
__global__ __launch_bounds__(256) void prep_kernel(
    const float* __restrict__ Q, const float* __restrict__ A,
    __bf16* __restrict__ Qp, __bf16* __restrict__ Ap,
    const int* __restrict__ qid, const float* __restrict__ ranks,
    const float* __restrict__ scores, float* __restrict__ w)
{
    const int tid = threadIdx.x;

    if (blockIdx.x >= NGROUPS) {
        // ---- pack part: one wave per fragment ----
        __shared__ __bf16 stile[4][16 * 40];   // per-wave 16 rows x 40 (pad)
        const int wid  = tid >> 6, lane = tid & 63;
        const int fid  = (blockIdx.x - NGROUPS) * 4 + wid;   // 0..16383
        const int m    = fid >> 13;                          // 0=Q, 1=A
        const int loc  = fid & 8191;                         // packed frag idx
        const int p    = loc >> 9;
        const int t    = (loc >> 4) & 31;
        const int fi   = loc & 15;

        const float* src = (m ? A : Q);
        __bf16*      dst = (m ? Ap : Qp) + (size_t)loc * FRAG_ELEMS;

        // coalesced read: lanes r*4..r*4+3 cover 64B of row r (full lines)
        const int r  = lane >> 2;        // 0..15
        const int kq = lane & 3;         // 0..3
        const size_t base = (size_t)(p * 256 + fi * 16 + r) * DIM + t * KC;
        const float4 v1 = *(const float4*)(src + base + kq * 4);
        const float4 v2 = *(const float4*)(src + base + 16 + kq * 4);
        bf16x4 b1, b2;
        b1[0] = (__bf16)v1.x; b1[1] = (__bf16)v1.y;
        b1[2] = (__bf16)v1.z; b1[3] = (__bf16)v1.w;
        b2[0] = (__bf16)v2.x; b2[1] = (__bf16)v2.y;
        b2[2] = (__bf16)v2.z; b2[3] = (__bf16)v2.w;

        *(bf16x4*)&stile[wid][r * 40 + kq * 4]      = b1;
        *(bf16x4*)&stile[wid][r * 40 + 16 + kq * 4] = b2;
        // same-wave LDS write->read: compiler inserts lgkmcnt wait
        bf16x8 g = *(const bf16x8*)&stile[wid][(lane & 15) * 40 + (lane >> 4) * 8];
        *(bf16x8*)&dst[lane * 8] = g;    // contiguous 1 KB per wave
        return;
    }

    // ---- group-weight part: one block (256 threads) per group ----
    const int g = blockIdx.x, lane = tid & 63, wv = tid >> 6;
    __shared__ float rmax[4], rmin[4], rsum[4];

    float gmax = -INFINITY, gmin = INFINITY;
    for (int j = tid; j < BATCH; j += 256) {
        if (qid[j] == g) {
            float s = scores[j];
            gmax = fmaxf(gmax, s);
            gmin = fminf(gmin, s);
        }
    }
    #pragma unroll
    for (int d = 1; d < 64; d <<= 1) {
        gmax = fmaxf(gmax, __shfl_xor(gmax, d, 64));
        gmin = fminf(gmin, __shfl_xor(gmin, d, 64));
    }
    if (lane == 0) { rmax[wv] = gmax; rmin[wv] = gmin; }
    __syncthreads();
    gmax = fmaxf(fmaxf(rmax[0], rmax[1]), fmaxf(rmax[2], rmax[3]));
    gmin = fminf(fminf(rmin[0], rmin[1]), fminf(rmin[2], rmin[3]));
    const float denom     = gmax - gmin;
    const float inv_denom = (denom > 0.f) ? 1.f / denom : 0.f;

    float lsum = 0.f;
    for (int j = tid; j < BATCH; j += 256) {
        if (qid[j] == g) {
            float norm = (scores[j] - gmin) * inv_denom;
            float u = __expf(-RANK_W * ranks[j] + SCORE_W * norm);
            w[j] = u;             // unnormalized; this thread owns j
            lsum += u;
        }
    }
    #pragma unroll
    for (int d = 1; d < 64; d <<= 1) lsum += __shfl_xor(lsum, d, 64);
    if (lane == 0) rsum[wv] = lsum;
    __syncthreads();
    const float wsum = rsum[0] + rsum[1] + rsum[2] + rsum[3];
    const float inv  = (wsum > 0.f) ? 1.f / wsum : 0.f;
    for (int j = tid; j < BATCH; j += 256) {
        if (qid[j] == g) w[j] *= inv;
    }
}

// ---------------------------------------------------------------------------
// Kernel 2: fused sim = (Q A^T)/T with online per-row (max, sumexp,
// weighted-sum, argmax) partials per 64-col slice.
// 256x256 tile, 16 waves of 64x64, PACKED operands -> contiguous 1KB
// global_load_lds streams, double-buffered prefetch, 1 barrier/iter.
// ---------------------------------------------------------------------------
__global__ __launch_bounds__(1024, 4) void fused_simloss_kernel(
    const __bf16* __restrict__ Qp, const __bf16* __restrict__ Ap,
    const int* __restrict__ qid, const float* __restrict__ w,
    float* __restrict__ Pm, float* __restrict__ Pl, float* __restrict__ Ps,
    float* __restrict__ Pbv, int* __restrict__ Pbi)
{
    __shared__ __bf16 sbuf[2][NFRAG * FRAG_ELEMS];   // 2 x 32 KB

    const int bid = blockIdx.x;                 // 0..255
    const int ib = bid >> 4, jb = bid & 15;
    const int i0 = ib * BI, j0 = jb * BJ;

    const int tid = threadIdx.x, wid = tid >> 6, lane = tid & 63;
    const int wm = wid >> 2, wn = wid & 3;      // 4x4 wave grid, 64x64 tiles
    const int quad = lane >> 4, l16 = lane & 15;

    floatx4 acc[4][4];
    #pragma unroll
    for (int m = 0; m < 4; ++m)
        #pragma unroll
        for (int n = 0; n < 4; ++n)
            #pragma unroll
            for (int c = 0; c < 4; ++c) acc[m][n][c] = 0.f;

    // staging: wave `wid` owns fragments f = wid*2, wid*2+1; packed source
    // advances by 16*512 elems per stage (fully contiguous per instruction).
    const __bf16* src[2];
    #pragma unroll
    for (int c = 0; c < 2; ++c) {
        const int f = wid * 2 + c;
        src[c] = (f < NFRAG_Q)
               ? Qp + ((size_t)(ib * NSTAGE * 16 + f)) * FRAG_ELEMS + lane * 8
               : Ap + ((size_t)(jb * NSTAGE * 16 + (f - NFRAG_Q))) * FRAG_ELEMS + lane * 8;
    }

    #define STAGE(buf, t)                                                     \
        do {                                                                  \
            _Pragma("unroll")                                                 \
            for (int c = 0; c < 2; ++c)                                       \
                ASYNC_COPY16(src[c] + (size_t)(t) * (16 * FRAG_ELEMS),        \
                             &sbuf[buf][(wid * 2 + c) * FRAG_ELEMS]);         \
        } while (0)

    STAGE(0, 0);   // prefetch stage 0

    for (int t = 0; t < NSTAGE; ++t) {
        __syncthreads();   // drains buf[t&1] copies (issued 1 iter ago) and
                           // orders prev reads of buf[(t+1)&1] before rewrite
        if (t + 1 < NSTAGE) STAGE((t + 1) & 1, t + 1);

        const __bf16* cur = sbuf[t & 1];
        bf16x8 qf[4], af[4];
        #pragma unroll
        for (int mf = 0; mf < 4; ++mf)
            qf[mf] = *(const bf16x8*)&cur[(wm * 4 + mf) * FRAG_ELEMS + lane * 8];
        #pragma unroll
        for (int nf = 0; nf < 4; ++nf)
            af[nf] = *(const bf16x8*)&cur[(NFRAG_Q + wn * 4 + nf) * FRAG_ELEMS + lane * 8];
        #pragma unroll
        for (int nf = 0; nf < 4; ++nf)
            #pragma unroll
            for (int mf = 0; mf < 4; ++mf)
                acc[mf][nf] = __builtin_amdgcn_mfma_f32_16x16x32_bf16(
                    qf[mf], af[nf], acc[mf][nf], 0, 0, 0);
    }
    #undef STAGE

    // ---- epilogue: online (m, l, s, argmax) per row within 64-col slice
    int cq[4]; float cw[4];
    #pragma unroll
    for (int n = 0; n < 4; ++n) {
        int col = j0 + wn * 64 + n * 16 + l16;
        cq[n] = qid[col];
        cw[n] = w[col];
    }
    const int slice = jb * 4 + wn;             // 0..63

    #pragma unroll
    for (int m = 0; m < 4; ++m) {
        #pragma unroll
        for (int reg = 0; reg < 4; ++reg) {
            const int row = i0 + wm * 64 + m * 16 + quad * 4 + reg;
            const int rq  = qid[row];

            float v[4];
            #pragma unroll
            for (int n = 0; n < 4; ++n) v[n] = acc[m][n][reg] * INV_T;

            float lm = fmaxf(fmaxf(v[0], v[1]), fmaxf(v[2], v[3]));
            float ll = __expf(v[0] - lm) + __expf(v[1] - lm) +
                       __expf(v[2] - lm) + __expf(v[3] - lm);
            float ls = 0.f;
            #pragma unroll
            for (int n = 0; n < 4; ++n) ls += (cq[n] == rq) ? cw[n] * v[n] : 0.f;

            float bv = v[0];
            int   bi = j0 + wn * 64 + l16;
            #pragma unroll
            for (int n = 1; n < 4; ++n) {
                int c = j0 + wn * 64 + n * 16 + l16;
                if (v[n] > bv) { bv = v[n]; bi = c; }
            }

            #pragma unroll
            for (int d = 1; d < 16; d <<= 1) {
                float om  = __shfl_xor(lm, d, 64);
                float ol  = __shfl_xor(ll, d, 64);
                float os  = __shfl_xor(ls, d, 64);
                float obv = __shfl_xor(bv, d, 64);
                int   obi = __shfl_xor(bi, d, 64);
                float nm = fmaxf(lm, om);
                ll = ll * __expf(lm - nm) + ol * __expf(om - nm);
                lm = nm;
                ls += os;
                if (obv > bv || (obv == bv && obi < bi)) { bv = obv; bi = obi; }
            }
            if (l16 == 0) {
                int idx = row * 64 + slice;
                Pm[idx] = lm; Pl[idx] = ll; Ps[idx] = ls;
                Pbv[idx] = bv; Pbi[idx] = bi;
            }
        }
    }
}

// ---------------------------------------------------------------------------
// Kernel 3: merge 64 slice-partials per row; per-block partial sums; the
// LAST arriving block reduces the 1024 partials and writes out[0..1].
// ---------------------------------------------------------------------------
__global__ __launch_bounds__(256) void row_reduce_kernel(
    const float* __restrict__ Pm, const float* __restrict__ Pl,
    const float* __restrict__ Ps, const float* __restrict__ Pbv,
    const int* __restrict__ Pbi, const int* __restrict__ qid,
    float* __restrict__ pb, unsigned int* __restrict__ ticket,
    float* __restrict__ out)
{
    const int wv   = threadIdx.x >> 6;
    const int r    = blockIdx.x * 4 + wv;
    const int lane = threadIdx.x & 63;
    const int idx  = r * 64 + lane;

    float m = Pm[idx], l = Pl[idx], s = Ps[idx], bv = Pbv[idx];
    int   bi = Pbi[idx];

    #pragma unroll
    for (int d = 1; d < 64; d <<= 1) {
        float om  = __shfl_xor(m, d, 64);
        float ol  = __shfl_xor(l, d, 64);
        float os  = __shfl_xor(s, d, 64);
        float obv = __shfl_xor(bv, d, 64);
        int   obi = __shfl_xor(bi, d, 64);
        float nm = fmaxf(m, om);
        l = l * __expf(m - nm) + ol * __expf(om - nm);
        m = nm;
        s += os;
        if (obv > bv || (obv == bv && obi < bi)) { bv = obv; bi = obi; }
    }

    __shared__ float sm[4], si[4];
    __shared__ int last_flag;
    if (lane == 0) {
        sm[wv] = (m + logf(l)) - s;
        si[wv] = (qid[bi] == qid[r]) ? 1.f : 0.f;
    }
    __syncthreads();
    if (threadIdx.x == 0) {
        pb[2 * blockIdx.x]     = (sm[0] + sm[1]) + (sm[2] + sm[3]);
        pb[2 * blockIdx.x + 1] = (si[0] + si[1]) + (si[2] + si[3]);
        __threadfence();                               // release partials
        unsigned int my = atomicAdd(ticket, 1u);       // device scope
        last_flag = (my == (BATCH / 4) - 1) ? 1 : 0;
    }
    __syncthreads();
    if (last_flag) {
        __threadfence();                               // acquire partials
        const volatile float* vpb = (const volatile float*)pb;
        float s1 = 0.f, s2 = 0.f;
        for (int i = threadIdx.x; i < BATCH / 4; i += 256) {
            s1 += vpb[2 * i];
            s2 += vpb[2 * i + 1];
        }
        #pragma unroll
        for (int d = 1; d < 64; d <<= 1) {
            s1 += __shfl_xor(s1, d, 64);
            s2 += __shfl_xor(s2, d, 64);
        }
        if (lane == 0) { sm[wv] = s1; si[wv] = s2; }
        __syncthreads();
        if (threadIdx.x == 0) {
            out[0] = ((sm[0] + sm[1]) + (sm[2] + sm[3])) * (1.f / (float)BATCH);
            out[1] = ((si[0] + si[1]) + (si[2] + si[3])) * (1.f / (float)BATCH);
        }
    }
}

// ---------------------------------------------------------------------------
extern "C" void kernel_launch(void* const* d_in, const int* in_sizes, int n_in,
                              void* d_out, int out_size, void* d_ws, size_t ws_size,
                              hipStream_t stream)
{
    const float* Q      = (const float*)d_in[0];
    const float* A      = (const float*)d_in[1];
    const int*   qid    = (const int*)d_in[2];
    const float* ranks  = (const float*)d_in[3];
    const float* scores = (const float*)d_in[4];
    float* out = (float*)d_out;

    // ws layout: Qp[4M bf16]=8MB | Ap[4M bf16]=8MB | w[4096] |
    //            Pm,Pl,Ps,Pbv[262144] | Pbi[262144] | pb[2048] | ticket
    __bf16* Qp = (__bf16*)d_ws;
    __bf16* Ap = Qp + (size_t)BATCH * DIM;
    float* w       = (float*)(Ap + (size_t)BATCH * DIM);
    float* Pm      = w + BATCH;
    float* Pl      = Pm + BATCH * 64;
    float* Ps      = Pl + BATCH * 64;
    float* Pbv     = Ps + BATCH * 64;
    int*   Pbi     = (int*)(Pbv + BATCH * 64);
    float* pb      = (float*)(Pbi + BATCH * 64);
    unsigned int* ticket = (unsigned int*)(pb + 2 * (BATCH / 4));

    hipMemsetAsync(ticket, 0, sizeof(unsigned int), stream);

    prep_kernel<<<NGROUPS + 4096, 256, 0, stream>>>(Q, A, Qp, Ap, qid, ranks, scores, w);

    fused_simloss_kernel<<<256, 1024, 0, stream>>>(Qp, Ap, qid, w, Pm, Pl, Ps, Pbv, Pbi);

    row_reduce_kernel<<<BATCH / 4, 256, 0, stream>>>(Pm, Pl, Ps, Pbv, Pbi, qid,
                                                     pb, ticket, out);
}